// Round 5
// baseline (116.495 us; speedup 1.0000x reference)
//
#include <hip/hip_runtime.h>
#include <hip/hip_bf16.h>
#include <stdint.h>

#define E_ 11
#define B_ 16
#define S_ 256
#define H_ 1024
#define L_ 32
#define GEPS 1e-4f

typedef __attribute__((ext_vector_type(8))) short short8;
typedef __attribute__((ext_vector_type(4))) float f32x4;

__device__ __forceinline__ unsigned short f2bf(float f) {
  unsigned u = __float_as_uint(f);
  unsigned r = (u + 0x7FFFu + ((u >> 16) & 1u)) >> 16;  // RNE
  return (unsigned short)r;
}
__device__ __forceinline__ float bf2f(unsigned short v) {
  return __uint_as_float(((unsigned)v) << 16);
}
__device__ __forceinline__ float sigf(float x) { return 1.0f / (1.0f + expf(-x)); }

// lang_id soft-argmax for batch b
__device__ __forceinline__ float lang_of(const float* __restrict__ logits, int b) {
  float lv[E_];
  float m = -1e30f;
  #pragma unroll
  for (int i = 0; i < E_; ++i) { lv[i] = logits[b * E_ + i]; m = fmaxf(m, lv[i]); }
  float den = 0.f, num = 0.f;
  #pragma unroll
  for (int i = 0; i < E_; ++i) {
    float z = expf((lv[i] - m) * 1000.0f);
    den += z; num += z * (float)i;
  }
  return num / den;
}

// conservative per-expert active flag (256-thread blocks): gate>1e-4 needs |lang-e|<1.66
__device__ __forceinline__ bool expert_active(const float* __restrict__ logits, int e) {
  int b = threadIdx.x & 15;
  float lang = lang_of(logits, b);
  unsigned long long m = __ballot(fabsf(lang - (float)e) < 1.7f);
  return m != 0ull;
}

// ============ prep: cvt x / W1 / W2 into MFMA-fragment-swizzled bf16 layouts ============
// xbfS:  [tile=b*4+sblk][kt 32][rowgrp 4][row16][l4 4] chunks of 16B (8 bf16)
// W1TS:  [u2=e*4+dt][kt 32][g 16][dl 16][l4 4] chunks of 16B  (element W1[k][d] -> d=(g,dl), k=(kt,l4,3b))
// W2T:   [e][l][k] row-major bf16 (k contiguous)
// grid = 2048 (x) + 2816 (W1) + 176 (W2), 256 threads
__global__ __launch_bounds__(256) void prep_kernel(
    const float* __restrict__ x, const float* __restrict__ logits,
    const float* __restrict__ W1, const float* __restrict__ W2,
    unsigned short* __restrict__ xbfS, unsigned short* __restrict__ W1TS,
    unsigned short* __restrict__ W2T) {
  int bid = blockIdx.x;
  int tid = threadIdx.x;
  __shared__ float t[64][65];

  if (bid < 2048) {  // x -> bf16, swizzled chunks
    int i = (bid * 256 + tid) * 8;
    float4 f0 = *(const float4*)(x + i);
    float4 f1 = *(const float4*)(x + i + 4);
    short8 o;
    o[0] = (short)f2bf(f0.x); o[1] = (short)f2bf(f0.y);
    o[2] = (short)f2bf(f0.z); o[3] = (short)f2bf(f0.w);
    o[4] = (short)f2bf(f1.x); o[5] = (short)f2bf(f1.y);
    o[6] = (short)f2bf(f1.z); o[7] = (short)f2bf(f1.w);
    int k = i & 1023, s = (i >> 10) & 255, b = i >> 18;
    int tile = b * 4 + (s >> 6), srow = s & 63;
    size_t chunk = ((((size_t)tile * 32 + (k >> 5)) * 4 + (srow >> 4)) * 16 + (srow & 15)) * 4
                   + ((k >> 3) & 3);
    *(short8*)(xbfS + chunk * 8) = o;
    return;
  }
  if (bid < 2048 + 2816) {  // W1 [e][k][d] -> swizzled W1TS
    int tt = bid - 2048;
    int e = tt >> 8, rest = tt & 255;
    int k0 = (rest >> 4) * 64, d0 = (rest & 15) * 64;
    if (!expert_active(logits, e)) return;
    int kr = tid >> 2, dc = (tid & 3) * 16;
    const float* src = W1 + ((size_t)e << 20) + (size_t)(k0 + kr) * H_ + d0 + dc;
    #pragma unroll
    for (int q = 0; q < 4; ++q) {
      float4 v = *(const float4*)(src + q * 4);
      t[kr][dc + q * 4 + 0] = v.x; t[kr][dc + q * 4 + 1] = v.y;
      t[kr][dc + q * 4 + 2] = v.z; t[kr][dc + q * 4 + 3] = v.w;
    }
    __syncthreads();
    int dr = tid >> 2, kc = (tid & 3) * 16;
    short8 v0, v1;
    #pragma unroll
    for (int j = 0; j < 8; ++j) v0[j] = (short)f2bf(t[kc + j][dr]);
    #pragma unroll
    for (int j = 0; j < 8; ++j) v1[j] = (short)f2bf(t[kc + 8 + j][dr]);
    int d = d0 + dr, k = k0 + kc;
    int dtq = d >> 8, g = (d & 255) >> 4, dl = d & 15;
    int ktq = k >> 5, l4q = (k >> 3) & 3;
    size_t chunk = ((((size_t)(e * 4 + dtq) * 32 + ktq) * 16 + g) * 16 + dl) * 4 + l4q;
    unsigned short* dst = W1TS + chunk * 8;
    *(short8*)(dst) = v0;
    *(short8*)(dst + 8) = v1;  // k+8 -> l4q+1, adjacent chunk
    return;
  }
  {  // W2 [e][k][l] -> W2T bf16 [e][l][k]
    int tt = bid - 4864;
    int e = tt >> 4, k0 = (tt & 15) * 64;
    if (!expert_active(logits, e)) return;
    int kr = tid >> 2, lc = (tid & 3) * 8;
    const float* src = W2 + (size_t)e * H_ * L_ + (size_t)(k0 + kr) * L_ + lc;
    float4 a = *(const float4*)(src);
    float4 b = *(const float4*)(src + 4);
    t[kr][lc + 0] = a.x; t[kr][lc + 1] = a.y; t[kr][lc + 2] = a.z; t[kr][lc + 3] = a.w;
    t[kr][lc + 4] = b.x; t[kr][lc + 5] = b.y; t[kr][lc + 6] = b.z; t[kr][lc + 7] = b.w;
    __syncthreads();
    int lr = tid >> 3, kc = (tid & 7) * 8;
    short8 v;
    #pragma unroll
    for (int j = 0; j < 8; ++j) v[j] = (short)f2bf(t[kc + j][lr]);
    *(short8*)(W2T + (size_t)(e * L_ + lr) * H_ + k0 + kc) = v;
  }
}

// ============ fused gated FFN: register-direct MFMA, no stage-1 LDS, no K-loop barriers ====
// block = (e,b,dt,sblk): M=64 x N=256 x K=1024. 512 threads = 8 waves (2 wr x 4 wc),
// each wave 32 rows x 64 cols. Fragments loaded straight from swizzled global (1KB
// coalesced per wave-load), double-buffered in registers. LDS only for P + reduce.
__global__ __launch_bounds__(512, 4) void ffn_kernel(
    const unsigned short* __restrict__ xbfS, const unsigned short* __restrict__ W1TS,
    const unsigned short* __restrict__ W2T, const float* __restrict__ b1,
    const float* __restrict__ b2, const float* __restrict__ logits,
    float* __restrict__ out) {
  int bid = blockIdx.x;
  int pid = bid >> 4;            // (e,b) pair [0,176)
  int q = bid & 15;
  int e = pid >> 4, b = pid & 15;
  int dt = q >> 2, sblk = q & 3, s0 = sblk * 64;
  float lang = lang_of(logits, b);
  float fe = (float)e;
  float g = sigf((lang - (fe - 0.5f)) * 8.0f) * sigf(((fe + 0.5f) - lang) * 8.0f);
  if (g < GEPS) return;

  __shared__ __align__(16) char smem[32768];  // 8 waves x 4KB (P strip / Tred overlay)

  int tid = threadIdx.x;
  int w = tid >> 6, wr = w >> 2, wc = w & 3;
  int l = tid & 63, l15 = l & 15, l4 = l >> 4;
  int lane8 = (l15 * 4 + l4) * 8;

  const unsigned short* pA0 =
      xbfS + ((size_t)(b * 4 + sblk) * 128 + wr * 2 + 0) * 512 + lane8;
  const unsigned short* pA1 = pA0 + 512;
  const unsigned short* pB0 =
      W1TS + ((size_t)(e * 4 + dt) * 512 + wc * 4 + 0) * 512 + lane8;
  const unsigned short* pB1 = pB0 + 512;
  const unsigned short* pB2 = pB0 + 1024;
  const unsigned short* pB3 = pB0 + 1536;

  float b1v[4];
  #pragma unroll
  for (int nf = 0; nf < 4; ++nf)
    b1v[nf] = b1[e * H_ + dt * 256 + wc * 64 + nf * 16 + l15];

  f32x4 acc[2][4];
  #pragma unroll
  for (int mf = 0; mf < 2; ++mf)
    #pragma unroll
    for (int nf = 0; nf < 4; ++nf) acc[mf][nf] = f32x4{0.f, 0.f, 0.f, 0.f};

  struct Frag { short8 a[2]; short8 b[4]; };
  Frag f0, f1;

  auto LD = [&](Frag& f, int kt) {
    size_t oA = (size_t)kt * 2048, oB = (size_t)kt * 8192;
    f.a[0] = *(const short8*)(pA0 + oA);
    f.a[1] = *(const short8*)(pA1 + oA);
    f.b[0] = *(const short8*)(pB0 + oB);
    f.b[1] = *(const short8*)(pB1 + oB);
    f.b[2] = *(const short8*)(pB2 + oB);
    f.b[3] = *(const short8*)(pB3 + oB);
  };
  auto FM = [&](const Frag& f) {
    __builtin_amdgcn_s_setprio(1);
    #pragma unroll
    for (int mf = 0; mf < 2; ++mf)
      #pragma unroll
      for (int nf = 0; nf < 4; ++nf)
        acc[mf][nf] =
            __builtin_amdgcn_mfma_f32_16x16x32_bf16(f.a[mf], f.b[nf], acc[mf][nf], 0, 0, 0);
    __builtin_amdgcn_s_setprio(0);
  };

  LD(f0, 0);
  #pragma unroll 1
  for (int kt = 0; kt < 30; kt += 2) {
    LD(f1, kt + 1);
    FM(f0);
    LD(f0, kt + 2);
    FM(f1);
  }
  LD(f1, 31);
  FM(f0);
  FM(f1);

  // relu(acc + b1) -> bf16 P strip (wave-private 4KB, XOR-swizzled 16B chunks)
  char* P = smem + w * 4096;
  #pragma unroll
  for (int mf = 0; mf < 2; ++mf)
    #pragma unroll
    for (int nf = 0; nf < 4; ++nf)
      #pragma unroll
      for (int rr = 0; rr < 4; ++rr) {
        int row = mf * 16 + l4 * 4 + rr;
        int col = nf * 16 + l15;
        float v = fmaxf(acc[mf][nf][rr] + b1v[nf], 0.f);
        *(unsigned short*)(P + row * 128 + (((col >> 3) ^ (row & 7)) * 16) +
                           (col & 7) * 2) = f2bf(v);
      }

  // stage 2: t_partial(32s x 32L) = P(32 x 64) @ W2T-slice
  f32x4 tacc[2][2];
  #pragma unroll
  for (int mf = 0; mf < 2; ++mf)
    #pragma unroll
    for (int nl = 0; nl < 2; ++nl) tacc[mf][nl] = f32x4{0.f, 0.f, 0.f, 0.f};
  #pragma unroll
  for (int kk = 0; kk < 2; ++kk) {
    short8 ap[2], bw[2];
    #pragma unroll
    for (int mf = 0; mf < 2; ++mf) {
      int row = mf * 16 + l15;
      int ch = kk * 4 + l4;
      ap[mf] = *(const short8*)(P + row * 128 + ((ch ^ (row & 7)) * 16));
    }
    #pragma unroll
    for (int nl = 0; nl < 2; ++nl)
      bw[nl] = *(const short8*)(W2T + (size_t)(e * L_ + nl * 16 + l15) * H_ +
                                dt * 256 + wc * 64 + kk * 32 + l4 * 8);
    #pragma unroll
    for (int mf = 0; mf < 2; ++mf)
      #pragma unroll
      for (int nl = 0; nl < 2; ++nl)
        tacc[mf][nl] =
            __builtin_amdgcn_mfma_f32_16x16x32_bf16(ap[mf], bw[nl], tacc[mf][nl], 0, 0, 0);
  }

  // per-wave t into LDS (overlays own P region), cross-wave (wc) reduce, atomicAdd
  float* Tr = (float*)smem + w * 1024;
  #pragma unroll
  for (int mf = 0; mf < 2; ++mf)
    #pragma unroll
    for (int nl = 0; nl < 2; ++nl)
      #pragma unroll
      for (int rr = 0; rr < 4; ++rr) {
        int row = mf * 16 + l4 * 4 + rr;
        int col = nl * 16 + l15;
        Tr[row * 32 + col] = tacc[mf][nl][rr];
      }
  __syncthreads();
  float* Tb = (float*)smem;
  #pragma unroll
  for (int jj = 0; jj < 4; ++jj) {
    int ei = tid + jj * 512;
    int srow = ei >> 5, lcol = ei & 31;
    int wr2 = srow >> 5, r5 = srow & 31;
    float sum = Tb[(wr2 * 4 + 0) * 1024 + r5 * 32 + lcol] +
                Tb[(wr2 * 4 + 1) * 1024 + r5 * 32 + lcol] +
                Tb[(wr2 * 4 + 2) * 1024 + r5 * 32 + lcol] +
                Tb[(wr2 * 4 + 3) * 1024 + r5 * 32 + lcol];
    if (dt == 0) sum += b2[e * L_ + lcol];
    atomicAdd(out + (size_t)(b * S_ + s0 + srow) * L_ + lcol, g * sum);
  }
}

// ---------------- fp32 fallback (no workspace needed) ----------------
__global__ void fb_kernel(const float* __restrict__ x, const float* __restrict__ logits,
                          const float* __restrict__ W1, const float* __restrict__ b1,
                          const float* __restrict__ W2, const float* __restrict__ b2,
                          float* __restrict__ out) {
  int bid = blockIdx.x;
  int e = bid >> 9;
  int r = bid & 511;
  int b = r >> 5, st = r & 31, s0 = st * 8;
  float lang = lang_of(logits, b);
  float fe = (float)e;
  float g = sigf((lang - (fe - 0.5f)) * 8.0f) * sigf(((fe + 0.5f) - lang) * 8.0f);
  if (g < GEPS) return;

  __shared__ float xs[8][H_];
  __shared__ unsigned short hs[8][H_];
  int tid = threadIdx.x;
  for (int jj = 0; jj < 32; ++jj) {
    int idx = tid + jj * 256;
    int s = idx >> 10, k = idx & 1023;
    xs[s][k] = x[(size_t)(b * S_ + s0 + s) * H_ + k];
  }
  __syncthreads();
  for (int qq = 0; qq < 4; ++qq) {
    int d = tid + qq * 256;
    float a[8];
    #pragma unroll
    for (int s = 0; s < 8; ++s) a[s] = 0.f;
    for (int k = 0; k < H_; ++k) {
      float wv = W1[((size_t)e << 20) + (size_t)k * H_ + d];
      #pragma unroll
      for (int s = 0; s < 8; ++s) a[s] += xs[s][k] * wv;
    }
    float bv = b1[e * H_ + d];
    #pragma unroll
    for (int s = 0; s < 8; ++s) hs[s][d] = f2bf(fmaxf(a[s] + bv, 0.f));
  }
  __syncthreads();
  int s = tid >> 5, lcol = tid & 31;
  float acc = 0.f;
  for (int d = 0; d < H_; ++d)
    acc += bf2f(hs[s][d]) * W2[(size_t)(e * H_ + d) * L_ + lcol];
  acc += b2[e * L_ + lcol];
  atomicAdd(out + (size_t)(b * S_ + s0 + s) * L_ + lcol, g * acc);
}

extern "C" void kernel_launch(void* const* d_in, const int* in_sizes, int n_in,
                              void* d_out, int out_size, void* d_ws, size_t ws_size,
                              hipStream_t stream) {
  (void)in_sizes; (void)n_in;
  const float* x  = (const float*)d_in[0];
  const float* lg = (const float*)d_in[1];
  const float* W1 = (const float*)d_in[2];
  const float* b1 = (const float*)d_in[3];
  const float* W2 = (const float*)d_in[4];
  const float* b2 = (const float*)d_in[5];
  float* out = (float*)d_out;

  hipMemsetAsync(d_out, 0, (size_t)out_size * sizeof(float), stream);

  const size_t OFF_X = 0;                          // 8 MB bf16 x (swizzled)
  const size_t OFF_W1 = OFF_X + 8388608;           // 22 MB bf16 W1 (swizzled)
  const size_t OFF_W2 = OFF_W1 + 23068672;         // 704 KB bf16 W2T
  const size_t WS_NEED = OFF_W2 + 720896;

  if (ws_size >= WS_NEED) {
    unsigned short* xbfS = (unsigned short*)((char*)d_ws + OFF_X);
    unsigned short* W1TS = (unsigned short*)((char*)d_ws + OFF_W1);
    unsigned short* W2T  = (unsigned short*)((char*)d_ws + OFF_W2);
    prep_kernel<<<2048 + 2816 + 176, 256, 0, stream>>>(x, lg, W1, W2, xbfS, W1TS, W2T);
    ffn_kernel<<<2816, 512, 0, stream>>>(xbfS, W1TS, W2T, b1, b2, lg, out);
  } else {
    fb_kernel<<<E_ * B_ * (S_ / 8), 256, 0, stream>>>(x, lg, W1, b1, W2, b2, out);
  }
}

// Round 6
// 76.320 us; speedup vs baseline: 1.5264x; 1.5264x over previous
//
#include <hip/hip_runtime.h>
#include <hip/hip_bf16.h>
#include <stdint.h>

#define E_ 11
#define B_ 16
#define S_ 256
#define H_ 1024
#define L_ 32
#define GEPS 1e-4f

typedef __attribute__((ext_vector_type(8))) short short8;
typedef __attribute__((ext_vector_type(4))) float f32x4;

__device__ __forceinline__ unsigned short f2bf(float f) {
  unsigned u = __float_as_uint(f);
  unsigned r = (u + 0x7FFFu + ((u >> 16) & 1u)) >> 16;  // RNE
  return (unsigned short)r;
}
__device__ __forceinline__ float bf2f(unsigned short v) {
  return __uint_as_float(((unsigned)v) << 16);
}
__device__ __forceinline__ void gload_lds16(const void* g, void* l) {
  __builtin_amdgcn_global_load_lds(
      (const __attribute__((address_space(1))) unsigned int*)g,
      (__attribute__((address_space(3))) unsigned int*)l, 16, 0, 0);
}
__device__ __forceinline__ float sigf(float x) { return 1.0f / (1.0f + expf(-x)); }

// lang_id soft-argmax for batch b
__device__ __forceinline__ float lang_of(const float* __restrict__ logits, int b) {
  float lv[E_];
  float m = -1e30f;
  #pragma unroll
  for (int i = 0; i < E_; ++i) { lv[i] = logits[b * E_ + i]; m = fmaxf(m, lv[i]); }
  float den = 0.f, num = 0.f;
  #pragma unroll
  for (int i = 0; i < E_; ++i) {
    float z = expf((lv[i] - m) * 1000.0f);
    den += z; num += z * (float)i;
  }
  return num / den;
}

// conservative per-expert active flag (256-thread blocks): gate>1e-4 needs |lang-e|<1.66
__device__ __forceinline__ bool expert_active(const float* __restrict__ logits, int e) {
  int b = threadIdx.x & 15;
  float lang = lang_of(logits, b);
  unsigned long long m = __ballot(fabsf(lang - (float)e) < 1.7f);
  return m != 0ull;
}

// ---------------- prep: cvt_x + cvt_w1 + cvt_w2 in one kernel ----------------
// xbf [B][S][H] bf16; W1T [E][d][k] bf16; W2T [E][l][k] bf16.
// grid = 2048 (x) + 2816 (W1) + 176 (W2), 256 threads
__global__ __launch_bounds__(256) void prep_kernel(
    const float* __restrict__ x, const float* __restrict__ logits,
    const float* __restrict__ W1, const float* __restrict__ W2,
    unsigned short* __restrict__ xbf, unsigned short* __restrict__ W1T,
    unsigned short* __restrict__ W2T) {
  int bid = blockIdx.x;
  int tid = threadIdx.x;
  __shared__ float t[64][65];

  if (bid < 2048) {  // x -> bf16
    int i = (bid * 256 + tid) * 8;
    float4 f0 = *(const float4*)(x + i);
    float4 f1 = *(const float4*)(x + i + 4);
    short8 o;
    o[0] = (short)f2bf(f0.x); o[1] = (short)f2bf(f0.y);
    o[2] = (short)f2bf(f0.z); o[3] = (short)f2bf(f0.w);
    o[4] = (short)f2bf(f1.x); o[5] = (short)f2bf(f1.y);
    o[6] = (short)f2bf(f1.z); o[7] = (short)f2bf(f1.w);
    *(short8*)(xbf + i) = o;
    return;
  }
  if (bid < 2048 + 2816) {  // W1 [e][k][d] -> W1T bf16 [e][d][k]
    int tt = bid - 2048;
    int e = tt >> 8, rest = tt & 255;
    int k0 = (rest >> 4) * 64, d0 = (rest & 15) * 64;
    if (!expert_active(logits, e)) return;
    int kr = tid >> 2, dc = (tid & 3) * 16;
    const float* src = W1 + ((size_t)e << 20) + (size_t)(k0 + kr) * H_ + d0 + dc;
    #pragma unroll
    for (int q = 0; q < 4; ++q) {
      float4 v = *(const float4*)(src + q * 4);
      t[kr][dc + q * 4 + 0] = v.x; t[kr][dc + q * 4 + 1] = v.y;
      t[kr][dc + q * 4 + 2] = v.z; t[kr][dc + q * 4 + 3] = v.w;
    }
    __syncthreads();
    int dr = tid >> 2, kc = (tid & 3) * 16;
    short8 v0, v1;
    #pragma unroll
    for (int j = 0; j < 8; ++j) v0[j] = (short)f2bf(t[kc + j][dr]);
    #pragma unroll
    for (int j = 0; j < 8; ++j) v1[j] = (short)f2bf(t[kc + 8 + j][dr]);
    unsigned short* dst = W1T + ((size_t)e << 20) + (size_t)(d0 + dr) * H_ + k0 + kc;
    *(short8*)(dst) = v0;
    *(short8*)(dst + 8) = v1;
    return;
  }
  {  // W2 [e][k][l] -> W2T bf16 [e][l][k]
    int tt = bid - 4864;
    int e = tt >> 4, k0 = (tt & 15) * 64;
    if (!expert_active(logits, e)) return;
    int kr = tid >> 2, lc = (tid & 3) * 8;
    const float* src = W2 + (size_t)e * H_ * L_ + (size_t)(k0 + kr) * L_ + lc;
    float4 a = *(const float4*)(src);
    float4 b = *(const float4*)(src + 4);
    t[kr][lc + 0] = a.x; t[kr][lc + 1] = a.y; t[kr][lc + 2] = a.z; t[kr][lc + 3] = a.w;
    t[kr][lc + 4] = b.x; t[kr][lc + 5] = b.y; t[kr][lc + 6] = b.z; t[kr][lc + 7] = b.w;
    __syncthreads();
    int lr = tid >> 3, kc = (tid & 7) * 8;
    short8 v;
    #pragma unroll
    for (int j = 0; j < 8; ++j) v[j] = (short)f2bf(t[kc + j][lr]);
    *(short8*)(W2T + (size_t)(e * L_ + lr) * H_ + k0 + kc) = v;
  }
}

#define WAITV(N) asm volatile("s_waitcnt vmcnt(" #N ")" ::: "memory")

// ============ fused gated FFN: 4-buffer LDS ring, 3-deep counted-vmcnt pipeline ============
// block = (e,b,dt,sblk): M=64 x N=256 x K=1024, BK=32. 256 thr = 4 waves, wave owns 64 d-cols.
// iter k: barrier(readers of buf[(k+3)&3] done) -> stage tile k+3 -> vmcnt(15) (stage k
// landed; k+1..k+3 in flight) -> barrier -> ds_read buf[k&3] -> MFMA. Never vmcnt(0) in loop.
// XCD map: unit u=(pair,dt) -> XCD u%8; 4 sblk blocks of a unit share the XCD (L2 reuse).
__global__ __launch_bounds__(256, 2) void ffn_kernel(
    const unsigned short* __restrict__ xbf, const unsigned short* __restrict__ W1T,
    const unsigned short* __restrict__ W2T, const float* __restrict__ b1,
    const float* __restrict__ b2, const float* __restrict__ logits,
    float* __restrict__ out) {
  int bid = blockIdx.x;
  int r8 = bid & 7, gq = bid >> 3;
  int sblk = gq & 3, uq = gq >> 2;      // uq in [0,88)
  int u = uq * 8 + r8;                  // (pair,dt) unit, XCD-pinned u%8
  int pair = u >> 2, dt = u & 3;
  int e = pair >> 4, b = pair & 15;
  int s0 = sblk * 64;
  float lang = lang_of(logits, b);
  float fe = (float)e;
  float g = sigf((lang - (fe - 0.5f)) * 8.0f) * sigf(((fe + 0.5f) - lang) * 8.0f);
  if (g < GEPS) return;

  __shared__ __align__(16) char smem[81920];  // 4 x (A 4KB + B 16KB)

  int tid = threadIdx.x;
  int w = tid >> 6, l = tid & 63;
  int l15 = l & 15, l4 = l >> 4;

  // ---- hoisted staging addresses (A: 1 chunk/lane, B: 4 chunks/lane) ----
  int c0 = tid;
  int p0 = c0 >> 3, sl0 = c0 & 7, uu0 = sl0 ^ (p0 & 7);
  const unsigned short* gA =
      xbf + (size_t)(b * S_ + s0 + p0 * 2 + (uu0 >> 2)) * H_ + (uu0 & 3) * 8;
  int ldsA = c0 * 16;
  const unsigned short* gB[4];
  int ldsB[4];
  #pragma unroll
  for (int jj = 0; jj < 4; ++jj) {
    int c = jj * 256 + tid;
    int p = c >> 3, slot = c & 7, uu = slot ^ (p & 7);
    gB[jj] = W1T + ((size_t)e * H_ + dt * 256 + p * 2 + (uu >> 2)) * H_ + (uu & 3) * 8;
    ldsB[jj] = 4096 + c * 16;
  }
  // ---- hoisted ds_read offsets (within one 20KB buffer) ----
  int offA[4], offB[4];
  #pragma unroll
  for (int mf = 0; mf < 4; ++mf) {
    int row = mf * 16 + l15;
    int p = row >> 1;
    int slot = (((row & 1) * 4) + l4) ^ (p & 7);
    offA[mf] = p * 128 + slot * 16;
  }
  #pragma unroll
  for (int nf = 0; nf < 4; ++nf) {
    int d = w * 64 + nf * 16 + l15;
    int p = d >> 1;
    int slot = (((d & 1) * 4) + l4) ^ (p & 7);
    offB[nf] = 4096 + p * 128 + slot * 16;
  }

  f32x4 acc[4][4];
  #pragma unroll
  for (int mf = 0; mf < 4; ++mf)
    #pragma unroll
    for (int nf = 0; nf < 4; ++nf) acc[mf][nf] = f32x4{0.f, 0.f, 0.f, 0.f};

  auto stage = [&](int buf, int kt) {
    int bb = buf * 20480;
    int ko = kt * 32;
    gload_lds16(gA + ko, smem + bb + ldsA);
    #pragma unroll
    for (int jj = 0; jj < 4; ++jj) gload_lds16(gB[jj] + ko, smem + bb + ldsB[jj]);
  };

  stage(0, 0);
  stage(1, 1);
  stage(2, 2);

  #pragma unroll
  for (int kt = 0; kt < 32; ++kt) {
    __builtin_amdgcn_s_barrier();            // readers of buf[(kt+3)&3] are done
    if (kt < 29) {
      stage((kt + 3) & 3, kt + 3);
      WAITV(15);                             // stage kt complete (k+1..k+3 in flight)
    } else if (kt == 29) {
      WAITV(10);
    } else if (kt == 30) {
      WAITV(5);
    } else {
      WAITV(0);
    }
    __builtin_amdgcn_s_barrier();            // tile kt ready for every wave
    int bb = (kt & 3) * 20480;
    short8 af[4], bf[4];
    #pragma unroll
    for (int mf = 0; mf < 4; ++mf) af[mf] = *(const short8*)(smem + bb + offA[mf]);
    #pragma unroll
    for (int nf = 0; nf < 4; ++nf) bf[nf] = *(const short8*)(smem + bb + offB[nf]);
    asm volatile("s_waitcnt lgkmcnt(0)" ::: "memory");
    __builtin_amdgcn_sched_barrier(0);
    __builtin_amdgcn_s_setprio(1);
    #pragma unroll
    for (int mf = 0; mf < 4; ++mf)
      #pragma unroll
      for (int nf = 0; nf < 4; ++nf)
        acc[mf][nf] =
            __builtin_amdgcn_mfma_f32_16x16x32_bf16(af[mf], bf[nf], acc[mf][nf], 0, 0, 0);
    __builtin_amdgcn_s_setprio(0);
  }

  float b1v[4];
  #pragma unroll
  for (int nf = 0; nf < 4; ++nf)
    b1v[nf] = b1[e * H_ + dt * 256 + w * 64 + nf * 16 + l15];

  // relu(acc + b1) -> bf16 P strip (wave-private 8KB at smem + w*8192; buffers 0-1 region,
  // safe: all waves past final barrier read only buf3)
  char* P = smem + w * 8192;
  #pragma unroll
  for (int mf = 0; mf < 4; ++mf)
    #pragma unroll
    for (int nf = 0; nf < 4; ++nf)
      #pragma unroll
      for (int rr = 0; rr < 4; ++rr) {
        int row = mf * 16 + l4 * 4 + rr;
        int col = nf * 16 + l15;
        float v = fmaxf(acc[mf][nf][rr] + b1v[nf], 0.f);
        *(unsigned short*)(P + row * 128 + (((col >> 3) ^ (row & 7)) * 16) +
                           (col & 7) * 2) = f2bf(v);
      }
  asm volatile("s_waitcnt lgkmcnt(0)" ::: "memory");

  // stage 2: t_partial = P @ W2T-slice (K = this wave's 64 d's)
  f32x4 tacc[4][2];
  #pragma unroll
  for (int mf = 0; mf < 4; ++mf)
    #pragma unroll
    for (int nl = 0; nl < 2; ++nl) tacc[mf][nl] = f32x4{0.f, 0.f, 0.f, 0.f};
  #pragma unroll
  for (int kk = 0; kk < 2; ++kk) {
    short8 ap[4], bw[2];
    #pragma unroll
    for (int mf = 0; mf < 4; ++mf) {
      int row = mf * 16 + l15;
      int ch = kk * 4 + l4;
      ap[mf] = *(const short8*)(P + row * 128 + ((ch ^ (row & 7)) * 16));
    }
    #pragma unroll
    for (int nl = 0; nl < 2; ++nl)
      bw[nl] = *(const short8*)(W2T + (size_t)(e * L_ + nl * 16 + l15) * H_ +
                                dt * 256 + w * 64 + kk * 32 + l4 * 8);
    #pragma unroll
    for (int mf = 0; mf < 4; ++mf)
      #pragma unroll
      for (int nl = 0; nl < 2; ++nl)
        tacc[mf][nl] =
            __builtin_amdgcn_mfma_f32_16x16x32_bf16(ap[mf], bw[nl], tacc[mf][nl], 0, 0, 0);
  }

  // cross-wave reduce of t_partial, (+ b2 if dt==0), * gate, atomicAdd to out
  float* Tred = (float*)smem;
  #pragma unroll
  for (int mf = 0; mf < 4; ++mf)
    #pragma unroll
    for (int nl = 0; nl < 2; ++nl)
      #pragma unroll
      for (int rr = 0; rr < 4; ++rr) {
        int row = mf * 16 + l4 * 4 + rr;
        int col = nl * 16 + l15;
        Tred[w * 2048 + row * 32 + col] = tacc[mf][nl][rr];
      }
  __syncthreads();
  #pragma unroll
  for (int jj = 0; jj < 8; ++jj) {
    int ei = tid + jj * 256;
    int srow = ei >> 5, lcol = ei & 31;
    float sum = Tred[ei] + Tred[2048 + ei] + Tred[4096 + ei] + Tred[6144 + ei];
    if (dt == 0) sum += b2[e * L_ + lcol];
    atomicAdd(out + (size_t)(b * S_ + s0 + srow) * L_ + lcol, g * sum);
  }
}

// ---------------- fp32 fallback (no workspace needed) ----------------
__global__ void fb_kernel(const float* __restrict__ x, const float* __restrict__ logits,
                          const float* __restrict__ W1, const float* __restrict__ b1,
                          const float* __restrict__ W2, const float* __restrict__ b2,
                          float* __restrict__ out) {
  int bid = blockIdx.x;
  int e = bid >> 9;
  int r = bid & 511;
  int b = r >> 5, st = r & 31, s0 = st * 8;
  float lang = lang_of(logits, b);
  float fe = (float)e;
  float g = sigf((lang - (fe - 0.5f)) * 8.0f) * sigf(((fe + 0.5f) - lang) * 8.0f);
  if (g < GEPS) return;

  __shared__ float xs[8][H_];
  __shared__ unsigned short hs[8][H_];
  int tid = threadIdx.x;
  for (int jj = 0; jj < 32; ++jj) {
    int idx = tid + jj * 256;
    int s = idx >> 10, k = idx & 1023;
    xs[s][k] = x[(size_t)(b * S_ + s0 + s) * H_ + k];
  }
  __syncthreads();
  for (int qq = 0; qq < 4; ++qq) {
    int d = tid + qq * 256;
    float a[8];
    #pragma unroll
    for (int s = 0; s < 8; ++s) a[s] = 0.f;
    for (int k = 0; k < H_; ++k) {
      float wv = W1[((size_t)e << 20) + (size_t)k * H_ + d];
      #pragma unroll
      for (int s = 0; s < 8; ++s) a[s] += xs[s][k] * wv;
    }
    float bv = b1[e * H_ + d];
    #pragma unroll
    for (int s = 0; s < 8; ++s) hs[s][d] = f2bf(fmaxf(a[s] + bv, 0.f));
  }
  __syncthreads();
  int s = tid >> 5, lcol = tid & 31;
  float acc = 0.f;
  for (int d = 0; d < H_; ++d)
    acc += bf2f(hs[s][d]) * W2[(size_t)(e * H_ + d) * L_ + lcol];
  acc += b2[e * L_ + lcol];
  atomicAdd(out + (size_t)(b * S_ + s0 + s) * L_ + lcol, g * acc);
}

extern "C" void kernel_launch(void* const* d_in, const int* in_sizes, int n_in,
                              void* d_out, int out_size, void* d_ws, size_t ws_size,
                              hipStream_t stream) {
  (void)in_sizes; (void)n_in;
  const float* x  = (const float*)d_in[0];
  const float* lg = (const float*)d_in[1];
  const float* W1 = (const float*)d_in[2];
  const float* b1 = (const float*)d_in[3];
  const float* W2 = (const float*)d_in[4];
  const float* b2 = (const float*)d_in[5];
  float* out = (float*)d_out;

  hipMemsetAsync(d_out, 0, (size_t)out_size * sizeof(float), stream);

  const size_t OFF_X = 0;                          // 8 MB bf16 x
  const size_t OFF_W1 = OFF_X + 8388608;           // 22 MB bf16 W1T
  const size_t OFF_W2 = OFF_W1 + 23068672;         // 704 KB bf16 W2T
  const size_t WS_NEED = OFF_W2 + 720896;

  if (ws_size >= WS_NEED) {
    unsigned short* xbf = (unsigned short*)((char*)d_ws + OFF_X);
    unsigned short* W1T = (unsigned short*)((char*)d_ws + OFF_W1);
    unsigned short* W2T = (unsigned short*)((char*)d_ws + OFF_W2);
    prep_kernel<<<2048 + 2816 + 176, 256, 0, stream>>>(x, lg, W1, W2, xbf, W1T, W2T);
    ffn_kernel<<<2816, 256, 0, stream>>>(xbf, W1T, W2T, b1, b2, lg, out);
  } else {
    fb_kernel<<<E_ * B_ * (S_ / 8), 256, 0, stream>>>(x, lg, W1, b1, W2, b2, out);
  }
}

// Round 7
// 66.306 us; speedup vs baseline: 1.7569x; 1.1510x over previous
//
#include <hip/hip_runtime.h>
#include <hip/hip_bf16.h>
#include <stdint.h>

#define E_ 11
#define B_ 16
#define S_ 256
#define H_ 1024
#define L_ 32
#define GEPS 1e-4f

typedef __attribute__((ext_vector_type(8))) short short8;
typedef __attribute__((ext_vector_type(4))) float f32x4;

__device__ __forceinline__ unsigned short f2bf(float f) {
  unsigned u = __float_as_uint(f);
  unsigned r = (u + 0x7FFFu + ((u >> 16) & 1u)) >> 16;  // RNE
  return (unsigned short)r;
}
__device__ __forceinline__ float bf2f(unsigned short v) {
  return __uint_as_float(((unsigned)v) << 16);
}
__device__ __forceinline__ void gload_lds16(const void* g, void* l) {
  __builtin_amdgcn_global_load_lds(
      (const __attribute__((address_space(1))) unsigned int*)g,
      (__attribute__((address_space(3))) unsigned int*)l, 16, 0, 0);
}
__device__ __forceinline__ float sigf(float x) { return 1.0f / (1.0f + expf(-x)); }

// lang_id soft-argmax for batch b
__device__ __forceinline__ float lang_of(const float* __restrict__ logits, int b) {
  float lv[E_];
  float m = -1e30f;
  #pragma unroll
  for (int i = 0; i < E_; ++i) { lv[i] = logits[b * E_ + i]; m = fmaxf(m, lv[i]); }
  float den = 0.f, num = 0.f;
  #pragma unroll
  for (int i = 0; i < E_; ++i) {
    float z = expf((lv[i] - m) * 1000.0f);
    den += z; num += z * (float)i;
  }
  return num / den;
}

// conservative per-expert active flag (256-thread blocks): gate>1e-4 needs |lang-e|<1.66
__device__ __forceinline__ bool expert_active(const float* __restrict__ logits, int e) {
  int b = threadIdx.x & 15;
  float lang = lang_of(logits, b);
  unsigned long long m = __ballot(fabsf(lang - (float)e) < 1.7f);
  return m != 0ull;
}

// ---------------- prep: cvt_x + cvt_w1 + cvt_w2 in one kernel ----------------
// xbf [B][S][H] bf16; W1T [E][d][k] bf16; W2T [E][l][k] bf16.
// grid = 2048 (x) + 2816 (W1) + 176 (W2), 256 threads
__global__ __launch_bounds__(256) void prep_kernel(
    const float* __restrict__ x, const float* __restrict__ logits,
    const float* __restrict__ W1, const float* __restrict__ W2,
    unsigned short* __restrict__ xbf, unsigned short* __restrict__ W1T,
    unsigned short* __restrict__ W2T) {
  int bid = blockIdx.x;
  int tid = threadIdx.x;
  __shared__ float t[64][65];

  if (bid < 2048) {  // x -> bf16
    int i = (bid * 256 + tid) * 8;
    float4 f0 = *(const float4*)(x + i);
    float4 f1 = *(const float4*)(x + i + 4);
    short8 o;
    o[0] = (short)f2bf(f0.x); o[1] = (short)f2bf(f0.y);
    o[2] = (short)f2bf(f0.z); o[3] = (short)f2bf(f0.w);
    o[4] = (short)f2bf(f1.x); o[5] = (short)f2bf(f1.y);
    o[6] = (short)f2bf(f1.z); o[7] = (short)f2bf(f1.w);
    *(short8*)(xbf + i) = o;
    return;
  }
  if (bid < 2048 + 2816) {  // W1 [e][k][d] -> W1T bf16 [e][d][k]
    int tt = bid - 2048;
    int e = tt >> 8, rest = tt & 255;
    int k0 = (rest >> 4) * 64, d0 = (rest & 15) * 64;
    if (!expert_active(logits, e)) return;
    int kr = tid >> 2, dc = (tid & 3) * 16;
    const float* src = W1 + ((size_t)e << 20) + (size_t)(k0 + kr) * H_ + d0 + dc;
    #pragma unroll
    for (int q = 0; q < 4; ++q) {
      float4 v = *(const float4*)(src + q * 4);
      t[kr][dc + q * 4 + 0] = v.x; t[kr][dc + q * 4 + 1] = v.y;
      t[kr][dc + q * 4 + 2] = v.z; t[kr][dc + q * 4 + 3] = v.w;
    }
    __syncthreads();
    int dr = tid >> 2, kc = (tid & 3) * 16;
    short8 v0, v1;
    #pragma unroll
    for (int j = 0; j < 8; ++j) v0[j] = (short)f2bf(t[kc + j][dr]);
    #pragma unroll
    for (int j = 0; j < 8; ++j) v1[j] = (short)f2bf(t[kc + 8 + j][dr]);
    unsigned short* dst = W1T + ((size_t)e << 20) + (size_t)(d0 + dr) * H_ + k0 + kc;
    *(short8*)(dst) = v0;
    *(short8*)(dst + 8) = v1;
    return;
  }
  {  // W2 [e][k][l] -> W2T bf16 [e][l][k]
    int tt = bid - 4864;
    int e = tt >> 4, k0 = (tt & 15) * 64;
    if (!expert_active(logits, e)) return;
    int kr = tid >> 2, lc = (tid & 3) * 8;
    const float* src = W2 + (size_t)e * H_ * L_ + (size_t)(k0 + kr) * L_ + lc;
    float4 a = *(const float4*)(src);
    float4 b = *(const float4*)(src + 4);
    t[kr][lc + 0] = a.x; t[kr][lc + 1] = a.y; t[kr][lc + 2] = a.z; t[kr][lc + 3] = a.w;
    t[kr][lc + 4] = b.x; t[kr][lc + 5] = b.y; t[kr][lc + 6] = b.z; t[kr][lc + 7] = b.w;
    __syncthreads();
    int lr = tid >> 3, kc = (tid & 7) * 8;
    short8 v;
    #pragma unroll
    for (int j = 0; j < 8; ++j) v[j] = (short)f2bf(t[kc + j][lr]);
    *(short8*)(W2T + (size_t)(e * L_ + lr) * H_ + k0 + kc) = v;
  }
}

#define WAITV(N) asm volatile("s_waitcnt vmcnt(" #N ")" ::: "memory")

// ============ fused gated FFN: 512thr/8wave, 3-buffer ring, counted-vmcnt pipeline ============
// block = (e,b,dt,sblk): M=128 x N=256 x K=1024, BK=32. 8 waves (2wr x 4wc), wave-tile 64x64.
// LDS/tile = A 8KB + B 16KB = 24KB; ring 3 = 72KB -> 2 blocks/CU = 4 waves/SIMD.
// iter kt: barrier -> stage tile kt+2 (3 chunks/thread, uniform) -> vmcnt(6) -> barrier
// -> ds_read buf[kt%3] -> MFMA. Tail: vmcnt(3)/(0). Never a full drain mid-loop.
__global__ __launch_bounds__(512, 4) void ffn_kernel(
    const unsigned short* __restrict__ xbf, const unsigned short* __restrict__ W1T,
    const unsigned short* __restrict__ W2T, const float* __restrict__ b1,
    const float* __restrict__ b2, const float* __restrict__ logits,
    float* __restrict__ out) {
  int bid = blockIdx.x;
  int r8 = bid & 7, gq = bid >> 3;
  int sblk = gq & 1, uq = gq >> 1;      // uq in [0,88)
  int u = uq * 8 + r8;                  // (pair,dt) unit, XCD-pinned u%8
  int pair = u >> 2, dt = u & 3;
  int e = pair >> 4, b = pair & 15;
  int s0 = sblk * 128;
  float lang = lang_of(logits, b);
  float fe = (float)e;
  float g = sigf((lang - (fe - 0.5f)) * 8.0f) * sigf(((fe + 0.5f) - lang) * 8.0f);
  if (g < GEPS) return;

  __shared__ __align__(16) char smem[73728];  // 3 x (A 8KB + B 16KB)

  int tid = threadIdx.x;
  int w = tid >> 6, wr = w >> 2, wc = w & 3;
  int l = tid & 63;
  int l15 = l & 15, l4 = l >> 4;

  // ---- hoisted staging addresses: A 1 chunk/thread, B 2 chunks/thread ----
  int pA = tid >> 3, slA = tid & 7, uA = slA ^ (pA & 7);
  const unsigned short* gA =
      xbf + (size_t)(b * S_ + s0 + pA * 2 + (uA >> 2)) * H_ + (uA & 3) * 8;
  int ldsA = tid * 16;
  const unsigned short* gB[2];
  int ldsB[2];
  #pragma unroll
  for (int jj = 0; jj < 2; ++jj) {
    int c = jj * 512 + tid;               // B chunk [0,1024)
    int p = c >> 3, slot = c & 7, uu = slot ^ (p & 7);
    gB[jj] = W1T + ((size_t)e * H_ + dt * 256 + p * 2 + (uu >> 2)) * H_ + (uu & 3) * 8;
    ldsB[jj] = 8192 + c * 16;
  }
  // ---- hoisted ds_read offsets (within one 24KB buffer) ----
  int offA[4], offB[4];
  #pragma unroll
  for (int mf = 0; mf < 4; ++mf) {
    int row = wr * 64 + mf * 16 + l15;    // [0,128)
    int p = row >> 1;
    int slot = (((row & 1) * 4) + l4) ^ (p & 7);
    offA[mf] = p * 128 + slot * 16;
  }
  #pragma unroll
  for (int nf = 0; nf < 4; ++nf) {
    int d = wc * 64 + nf * 16 + l15;      // [0,256)
    int p = d >> 1;
    int slot = (((d & 1) * 4) + l4) ^ (p & 7);
    offB[nf] = 8192 + p * 128 + slot * 16;
  }

  f32x4 acc[4][4];
  #pragma unroll
  for (int mf = 0; mf < 4; ++mf)
    #pragma unroll
    for (int nf = 0; nf < 4; ++nf) acc[mf][nf] = f32x4{0.f, 0.f, 0.f, 0.f};

  auto stage = [&](int buf, int kt) {
    int bb = buf * 24576;
    int ko = kt * 32;
    gload_lds16(gA + ko, smem + bb + ldsA);
    gload_lds16(gB[0] + ko, smem + bb + ldsB[0]);
    gload_lds16(gB[1] + ko, smem + bb + ldsB[1]);
  };

  stage(0, 0);
  stage(1, 1);

  #pragma unroll
  for (int kt = 0; kt < 32; ++kt) {
    __builtin_amdgcn_s_barrier();            // readers of buf[(kt+2)%3] are done
    if (kt < 30) {
      stage((kt + 2) % 3, kt + 2);
      WAITV(6);                              // stage kt landed; kt+1,kt+2 in flight
    } else if (kt == 30) {
      WAITV(3);
    } else {
      WAITV(0);
    }
    __builtin_amdgcn_s_barrier();            // tile kt ready for every wave
    int bb = (kt % 3) * 24576;
    short8 af[4], bf[4];
    #pragma unroll
    for (int mf = 0; mf < 4; ++mf) af[mf] = *(const short8*)(smem + bb + offA[mf]);
    #pragma unroll
    for (int nf = 0; nf < 4; ++nf) bf[nf] = *(const short8*)(smem + bb + offB[nf]);
    asm volatile("s_waitcnt lgkmcnt(0)" ::: "memory");
    __builtin_amdgcn_sched_barrier(0);
    __builtin_amdgcn_s_setprio(1);
    #pragma unroll
    for (int mf = 0; mf < 4; ++mf)
      #pragma unroll
      for (int nf = 0; nf < 4; ++nf)
        acc[mf][nf] =
            __builtin_amdgcn_mfma_f32_16x16x32_bf16(af[mf], bf[nf], acc[mf][nf], 0, 0, 0);
    __builtin_amdgcn_s_setprio(0);
  }

  __syncthreads();  // ring buffers about to be overlaid by P strips

  float b1v[4];
  #pragma unroll
  for (int nf = 0; nf < 4; ++nf)
    b1v[nf] = b1[e * H_ + dt * 256 + wc * 64 + nf * 16 + l15];

  // relu(acc + b1) -> bf16 P strip (wave-private 8KB at smem + w*8192)
  char* P = smem + w * 8192;
  #pragma unroll
  for (int mf = 0; mf < 4; ++mf)
    #pragma unroll
    for (int nf = 0; nf < 4; ++nf)
      #pragma unroll
      for (int rr = 0; rr < 4; ++rr) {
        int row = mf * 16 + l4 * 4 + rr;   // wave-local row [0,64)
        int col = nf * 16 + l15;           // wave-local d [0,64)
        float v = fmaxf(acc[mf][nf][rr] + b1v[nf], 0.f);
        *(unsigned short*)(P + row * 128 + (((col >> 3) ^ (row & 7)) * 16) +
                           (col & 7) * 2) = f2bf(v);
      }
  asm volatile("s_waitcnt lgkmcnt(0)" ::: "memory");

  // stage 2: t_partial(64s x 32L) = P(64 x 64) @ W2T-slice (K = wave's 64 d's)
  f32x4 tacc[4][2];
  #pragma unroll
  for (int mf = 0; mf < 4; ++mf)
    #pragma unroll
    for (int nl = 0; nl < 2; ++nl) tacc[mf][nl] = f32x4{0.f, 0.f, 0.f, 0.f};
  #pragma unroll
  for (int kk = 0; kk < 2; ++kk) {
    short8 ap[4], bw[2];
    #pragma unroll
    for (int mf = 0; mf < 4; ++mf) {
      int row = mf * 16 + l15;
      int ch = kk * 4 + l4;
      ap[mf] = *(const short8*)(P + row * 128 + ((ch ^ (row & 7)) * 16));
    }
    #pragma unroll
    for (int nl = 0; nl < 2; ++nl)
      bw[nl] = *(const short8*)(W2T + (size_t)(e * L_ + nl * 16 + l15) * H_ +
                                dt * 256 + wc * 64 + kk * 32 + l4 * 8);
    #pragma unroll
    for (int mf = 0; mf < 4; ++mf)
      #pragma unroll
      for (int nl = 0; nl < 2; ++nl)
        tacc[mf][nl] =
            __builtin_amdgcn_mfma_f32_16x16x32_bf16(ap[mf], bw[nl], tacc[mf][nl], 0, 0, 0);
  }

  // per-wave t (64x32 f32 = 8KB, overlays own P), cross-wc reduce, atomicAdd
  float* Tr = (float*)smem + w * 2048;
  #pragma unroll
  for (int mf = 0; mf < 4; ++mf)
    #pragma unroll
    for (int nl = 0; nl < 2; ++nl)
      #pragma unroll
      for (int rr = 0; rr < 4; ++rr) {
        int row = mf * 16 + l4 * 4 + rr;
        int col = nl * 16 + l15;
        Tr[row * 32 + col] = tacc[mf][nl][rr];
      }
  __syncthreads();
  float* Tb = (float*)smem;
  #pragma unroll
  for (int jj = 0; jj < 8; ++jj) {
    int ei = tid + jj * 512;               // [0,4096) = 128 rows x 32 cols
    int srow = ei >> 5, lcol = ei & 31;
    int wr2 = srow >> 6, r6 = srow & 63;
    float sum = Tb[(wr2 * 4 + 0) * 2048 + r6 * 32 + lcol] +
                Tb[(wr2 * 4 + 1) * 2048 + r6 * 32 + lcol] +
                Tb[(wr2 * 4 + 2) * 2048 + r6 * 32 + lcol] +
                Tb[(wr2 * 4 + 3) * 2048 + r6 * 32 + lcol];
    if (dt == 0) sum += b2[e * L_ + lcol];
    atomicAdd(out + (size_t)(b * S_ + s0 + srow) * L_ + lcol, g * sum);
  }
}

// ---------------- fp32 fallback (no workspace needed) ----------------
__global__ void fb_kernel(const float* __restrict__ x, const float* __restrict__ logits,
                          const float* __restrict__ W1, const float* __restrict__ b1,
                          const float* __restrict__ W2, const float* __restrict__ b2,
                          float* __restrict__ out) {
  int bid = blockIdx.x;
  int e = bid >> 9;
  int r = bid & 511;
  int b = r >> 5, st = r & 31, s0 = st * 8;
  float lang = lang_of(logits, b);
  float fe = (float)e;
  float g = sigf((lang - (fe - 0.5f)) * 8.0f) * sigf(((fe + 0.5f) - lang) * 8.0f);
  if (g < GEPS) return;

  __shared__ float xs[8][H_];
  __shared__ unsigned short hs[8][H_];
  int tid = threadIdx.x;
  for (int jj = 0; jj < 32; ++jj) {
    int idx = tid + jj * 256;
    int s = idx >> 10, k = idx & 1023;
    xs[s][k] = x[(size_t)(b * S_ + s0 + s) * H_ + k];
  }
  __syncthreads();
  for (int qq = 0; qq < 4; ++qq) {
    int d = tid + qq * 256;
    float a[8];
    #pragma unroll
    for (int s = 0; s < 8; ++s) a[s] = 0.f;
    for (int k = 0; k < H_; ++k) {
      float wv = W1[((size_t)e << 20) + (size_t)k * H_ + d];
      #pragma unroll
      for (int s = 0; s < 8; ++s) a[s] += xs[s][k] * wv;
    }
    float bv = b1[e * H_ + d];
    #pragma unroll
    for (int s = 0; s < 8; ++s) hs[s][d] = f2bf(fmaxf(a[s] + bv, 0.f));
  }
  __syncthreads();
  int s = tid >> 5, lcol = tid & 31;
  float acc = 0.f;
  for (int d = 0; d < H_; ++d)
    acc += bf2f(hs[s][d]) * W2[(size_t)(e * H_ + d) * L_ + lcol];
  acc += b2[e * L_ + lcol];
  atomicAdd(out + (size_t)(b * S_ + s0 + s) * L_ + lcol, g * acc);
}

extern "C" void kernel_launch(void* const* d_in, const int* in_sizes, int n_in,
                              void* d_out, int out_size, void* d_ws, size_t ws_size,
                              hipStream_t stream) {
  (void)in_sizes; (void)n_in;
  const float* x  = (const float*)d_in[0];
  const float* lg = (const float*)d_in[1];
  const float* W1 = (const float*)d_in[2];
  const float* b1 = (const float*)d_in[3];
  const float* W2 = (const float*)d_in[4];
  const float* b2 = (const float*)d_in[5];
  float* out = (float*)d_out;

  hipMemsetAsync(d_out, 0, (size_t)out_size * sizeof(float), stream);

  const size_t OFF_X = 0;                          // 8 MB bf16 x
  const size_t OFF_W1 = OFF_X + 8388608;           // 22 MB bf16 W1T
  const size_t OFF_W2 = OFF_W1 + 23068672;         // 704 KB bf16 W2T
  const size_t WS_NEED = OFF_W2 + 720896;

  if (ws_size >= WS_NEED) {
    unsigned short* xbf = (unsigned short*)((char*)d_ws + OFF_X);
    unsigned short* W1T = (unsigned short*)((char*)d_ws + OFF_W1);
    unsigned short* W2T = (unsigned short*)((char*)d_ws + OFF_W2);
    prep_kernel<<<2048 + 2816 + 176, 256, 0, stream>>>(x, lg, W1, W2, xbf, W1T, W2T);
    // 8 XCD lanes x 88 uq x 2 sblk: unit u=(pair,dt) pinned to XCD u%8
    ffn_kernel<<<8 * 88 * 2, 512, 0, stream>>>(xbf, W1T, W2T, b1, b2, lg, out);
  } else {
    fb_kernel<<<E_ * B_ * (S_ / 8), 256, 0, stream>>>(x, lg, W1, b1, W2, b2, out);
  }
}

// Round 8
// 65.091 us; speedup vs baseline: 1.7897x; 1.0187x over previous
//
#include <hip/hip_runtime.h>
#include <hip/hip_bf16.h>
#include <stdint.h>

#define E_ 11
#define B_ 16
#define S_ 256
#define H_ 1024
#define L_ 32
#define GEPS 1e-4f

typedef __attribute__((ext_vector_type(8))) short short8;
typedef __attribute__((ext_vector_type(4))) float f32x4;

__device__ __forceinline__ unsigned short f2bf(float f) {
  unsigned u = __float_as_uint(f);
  unsigned r = (u + 0x7FFFu + ((u >> 16) & 1u)) >> 16;  // RNE
  return (unsigned short)r;
}
__device__ __forceinline__ float bf2f(unsigned short v) {
  return __uint_as_float(((unsigned)v) << 16);
}
__device__ __forceinline__ void gload_lds16(const void* g, void* l) {
  __builtin_amdgcn_global_load_lds(
      (const __attribute__((address_space(1))) unsigned int*)g,
      (__attribute__((address_space(3))) unsigned int*)l, 16, 0, 0);
}
__device__ __forceinline__ float sigf(float x) { return 1.0f / (1.0f + expf(-x)); }

// lang_id soft-argmax for batch b
__device__ __forceinline__ float lang_of(const float* __restrict__ logits, int b) {
  float lv[E_];
  float m = -1e30f;
  #pragma unroll
  for (int i = 0; i < E_; ++i) { lv[i] = logits[b * E_ + i]; m = fmaxf(m, lv[i]); }
  float den = 0.f, num = 0.f;
  #pragma unroll
  for (int i = 0; i < E_; ++i) {
    float z = expf((lv[i] - m) * 1000.0f);
    den += z; num += z * (float)i;
  }
  return num / den;
}
__device__ __forceinline__ float gate_of(float lang, int e) {
  float fe = (float)e;
  return sigf((lang - (fe - 0.5f)) * 8.0f) * sigf(((fe + 0.5f) - lang) * 8.0f);
}

// conservative per-expert active flag (256-thread blocks)
__device__ __forceinline__ bool expert_active(const float* __restrict__ logits, int e) {
  int b = threadIdx.x & 15;
  float lang = lang_of(logits, b);
  unsigned long long m = __ballot(fabsf(lang - (float)e) < 1.7f);
  return m != 0ull;
}

// ---------------- prep: cvt_x + cvt_w1 + cvt_w2 + plan (compacted active-pair list) -----
// xbf [B][S][H] bf16; W1T [E][d][k] bf16; W2T [E][l][k] bf16; plan: [cnt, pair0, pair1, ...]
// grid = 2048 (x) + 2816 (W1) + 176 (W2) + 1 (plan), 256 threads
__global__ __launch_bounds__(256) void prep_kernel(
    const float* __restrict__ x, const float* __restrict__ logits,
    const float* __restrict__ W1, const float* __restrict__ W2,
    unsigned short* __restrict__ xbf, unsigned short* __restrict__ W1T,
    unsigned short* __restrict__ W2T, int* __restrict__ plan) {
  int bid = blockIdx.x;
  int tid = threadIdx.x;
  __shared__ float t[64][65];

  if (bid < 2048) {  // x -> bf16
    int i = (bid * 256 + tid) * 8;
    float4 f0 = *(const float4*)(x + i);
    float4 f1 = *(const float4*)(x + i + 4);
    short8 o;
    o[0] = (short)f2bf(f0.x); o[1] = (short)f2bf(f0.y);
    o[2] = (short)f2bf(f0.z); o[3] = (short)f2bf(f0.w);
    o[4] = (short)f2bf(f1.x); o[5] = (short)f2bf(f1.y);
    o[6] = (short)f2bf(f1.z); o[7] = (short)f2bf(f1.w);
    *(short8*)(xbf + i) = o;
    return;
  }
  if (bid < 2048 + 2816) {  // W1 [e][k][d] -> W1T bf16 [e][d][k]
    int tt = bid - 2048;
    int e = tt >> 8, rest = tt & 255;
    int k0 = (rest >> 4) * 64, d0 = (rest & 15) * 64;
    if (!expert_active(logits, e)) return;
    int kr = tid >> 2, dc = (tid & 3) * 16;
    const float* src = W1 + ((size_t)e << 20) + (size_t)(k0 + kr) * H_ + d0 + dc;
    #pragma unroll
    for (int q = 0; q < 4; ++q) {
      float4 v = *(const float4*)(src + q * 4);
      t[kr][dc + q * 4 + 0] = v.x; t[kr][dc + q * 4 + 1] = v.y;
      t[kr][dc + q * 4 + 2] = v.z; t[kr][dc + q * 4 + 3] = v.w;
    }
    __syncthreads();
    int dr = tid >> 2, kc = (tid & 3) * 16;
    short8 v0, v1;
    #pragma unroll
    for (int j = 0; j < 8; ++j) v0[j] = (short)f2bf(t[kc + j][dr]);
    #pragma unroll
    for (int j = 0; j < 8; ++j) v1[j] = (short)f2bf(t[kc + 8 + j][dr]);
    unsigned short* dst = W1T + ((size_t)e << 20) + (size_t)(d0 + dr) * H_ + k0 + kc;
    *(short8*)(dst) = v0;
    *(short8*)(dst + 8) = v1;
    return;
  }
  if (bid < 2048 + 2816 + 176) {  // W2 [e][k][l] -> W2T bf16 [e][l][k]
    int tt = bid - 4864;
    int e = tt >> 4, k0 = (tt & 15) * 64;
    if (!expert_active(logits, e)) return;
    int kr = tid >> 2, lc = (tid & 3) * 8;
    const float* src = W2 + (size_t)e * H_ * L_ + (size_t)(k0 + kr) * L_ + lc;
    float4 a = *(const float4*)(src);
    float4 b = *(const float4*)(src + 4);
    t[kr][lc + 0] = a.x; t[kr][lc + 1] = a.y; t[kr][lc + 2] = a.z; t[kr][lc + 3] = a.w;
    t[kr][lc + 4] = b.x; t[kr][lc + 5] = b.y; t[kr][lc + 6] = b.z; t[kr][lc + 7] = b.w;
    __syncthreads();
    int lr = tid >> 3, kc = (tid & 7) * 8;
    short8 v;
    #pragma unroll
    for (int j = 0; j < 8; ++j) v[j] = (short)f2bf(t[kc + j][lr]);
    *(short8*)(W2T + (size_t)(e * L_ + lr) * H_ + k0 + kc) = v;
    return;
  }
  {  // plan block: ballot-compacted list of active (e,b) pairs, deterministic order
    __shared__ float langs[16];
    __shared__ int wcnt[4];
    if (tid < 16) langs[tid] = lang_of(logits, tid);
    __syncthreads();
    bool act = false;
    if (tid < E_ * B_) {
      int e = tid >> 4, b = tid & 15;
      act = gate_of(langs[b], e) >= GEPS;
    }
    unsigned long long m = __ballot(act);
    int w = tid >> 6;
    if ((tid & 63) == 0) wcnt[w] = __popcll(m);
    __syncthreads();
    int off = 0;
    for (int i = 0; i < w; ++i) off += wcnt[i];
    int rank = __popcll(m & ((1ull << (tid & 63)) - 1ull));
    if (act) plan[1 + off + rank] = tid;
    if (tid == 0) plan[0] = wcnt[0] + wcnt[1] + wcnt[2] + wcnt[3];
  }
}

#define WAITV(N) asm volatile("s_waitcnt vmcnt(" #N ")" ::: "memory")

// ===== fused gated FFN: 256x256 tile, wave-tile 64x128, 3-ring counted-vmcnt, 1 block/CU =====
// block = (active pair, dt): M=256 (all S of batch b) x N=256 x K=1024, BK=32.
// 512 thr = 8 waves (4wr x 2wc). LDS = 3 x (A 16KB + B 16KB) = 96KB -> 1 block/CU, 2 waves/SIMD.
// iter kt: barrier -> stage kt+2 (4 chunks/thr) -> vmcnt(8) -> barrier -> ds_read -> 32 MFMA.
__global__ __launch_bounds__(512, 2) void ffn_kernel(
    const unsigned short* __restrict__ xbf, const unsigned short* __restrict__ W1T,
    const unsigned short* __restrict__ W2T, const float* __restrict__ b1,
    const float* __restrict__ b2, const float* __restrict__ logits,
    const int* __restrict__ plan, float* __restrict__ out) {
  int bid = blockIdx.x;
  int cnt = plan[0];
  if (bid >= (cnt << 2)) return;
  int pair = plan[1 + (bid >> 2)];
  int dt = bid & 3;
  int e = pair >> 4, b = pair & 15;
  float g = gate_of(lang_of(logits, b), e);

  __shared__ __align__(16) char smem[98304];  // 3 x 32KB

  int tid = threadIdx.x;
  int w = tid >> 6, wr = w >> 1, wc = w & 1;
  int l = tid & 63, l15 = l & 15, l4 = l >> 4;

  // ---- hoisted staging addresses: A 2 chunks/thread, B 2 chunks/thread ----
  const unsigned short* gA[2]; int ldsA[2];
  const unsigned short* gB[2]; int ldsB[2];
  #pragma unroll
  for (int jj = 0; jj < 2; ++jj) {
    int c = jj * 512 + tid;              // [0,1024)
    int p = c >> 3, uu = (c & 7) ^ (p & 7);
    int row = p * 2 + (uu >> 2), kc = (uu & 3) * 8;
    gA[jj] = xbf + (size_t)(b * S_ + row) * H_ + kc;
    ldsA[jj] = c * 16;
    gB[jj] = W1T + ((size_t)e * H_ + dt * 256 + row) * H_ + kc;
    ldsB[jj] = 16384 + c * 16;
  }
  // ---- hoisted ds_read offsets (within one 32KB buffer) ----
  int offA[4], offB[8];
  #pragma unroll
  for (int mf = 0; mf < 4; ++mf) {
    int row = wr * 64 + mf * 16 + l15;   // [0,256)
    int p = row >> 1;
    int slot = (((row & 1) * 4) + l4) ^ (p & 7);
    offA[mf] = p * 128 + slot * 16;
  }
  #pragma unroll
  for (int nf = 0; nf < 8; ++nf) {
    int d = wc * 128 + nf * 16 + l15;    // [0,256)
    int p = d >> 1;
    int slot = (((d & 1) * 4) + l4) ^ (p & 7);
    offB[nf] = 16384 + p * 128 + slot * 16;
  }

  f32x4 acc[4][8];
  #pragma unroll
  for (int mf = 0; mf < 4; ++mf)
    #pragma unroll
    for (int nf = 0; nf < 8; ++nf) acc[mf][nf] = f32x4{0.f, 0.f, 0.f, 0.f};

  auto stage = [&](int buf, int kt) {
    int bb = buf * 32768;
    int ko = kt * 32;
    gload_lds16(gA[0] + ko, smem + bb + ldsA[0]);
    gload_lds16(gA[1] + ko, smem + bb + ldsA[1]);
    gload_lds16(gB[0] + ko, smem + bb + ldsB[0]);
    gload_lds16(gB[1] + ko, smem + bb + ldsB[1]);
  };

  stage(0, 0);
  stage(1, 1);

  #pragma unroll
  for (int kt = 0; kt < 32; ++kt) {
    __builtin_amdgcn_s_barrier();            // readers of buf[(kt+2)%3] (== kt-1) done
    if (kt < 30) {
      stage((kt + 2) % 3, kt + 2);
      WAITV(8);                              // stage kt landed; kt+1,kt+2 in flight
    } else if (kt == 30) {
      WAITV(4);
    } else {
      WAITV(0);
    }
    __builtin_amdgcn_s_barrier();            // tile kt ready for every wave
    int bb = (kt % 3) * 32768;
    short8 af[4], bf[8];
    #pragma unroll
    for (int mf = 0; mf < 4; ++mf) af[mf] = *(const short8*)(smem + bb + offA[mf]);
    #pragma unroll
    for (int nf = 0; nf < 8; ++nf) bf[nf] = *(const short8*)(smem + bb + offB[nf]);
    asm volatile("s_waitcnt lgkmcnt(0)" ::: "memory");
    __builtin_amdgcn_sched_barrier(0);
    __builtin_amdgcn_s_setprio(1);
    #pragma unroll
    for (int mf = 0; mf < 4; ++mf)
      #pragma unroll
      for (int nf = 0; nf < 8; ++nf)
        acc[mf][nf] =
            __builtin_amdgcn_mfma_f32_16x16x32_bf16(af[mf], bf[nf], acc[mf][nf], 0, 0, 0);
    __builtin_amdgcn_s_setprio(0);
  }

  __syncthreads();  // ring buffers about to be overlaid by P strips / Tred

  float b1v[8];
  #pragma unroll
  for (int nf = 0; nf < 8; ++nf)
    b1v[nf] = b1[e * H_ + dt * 256 + wc * 128 + nf * 16 + l15];

  // stage 2 in two 64-d halves: P strip (wave-private 8KB) -> tacc += P @ W2T
  char* P = smem + w * 8192;
  f32x4 tacc[4][2];
  #pragma unroll
  for (int mf = 0; mf < 4; ++mf)
    #pragma unroll
    for (int nl = 0; nl < 2; ++nl) tacc[mf][nl] = f32x4{0.f, 0.f, 0.f, 0.f};

  #pragma unroll
  for (int half = 0; half < 2; ++half) {
    #pragma unroll
    for (int mf = 0; mf < 4; ++mf)
      #pragma unroll
      for (int nfh = 0; nfh < 4; ++nfh) {
        int nf = half * 4 + nfh;
        #pragma unroll
        for (int rr = 0; rr < 4; ++rr) {
          int row = mf * 16 + l4 * 4 + rr;   // wave-local s row [0,64)
          int col = nfh * 16 + l15;          // half-local d [0,64)
          float v = fmaxf(acc[mf][nf][rr] + b1v[nf], 0.f);
          *(unsigned short*)(P + row * 128 + (((col >> 3) ^ (row & 7)) * 16) +
                             (col & 7) * 2) = f2bf(v);
        }
      }
    asm volatile("s_waitcnt lgkmcnt(0)" ::: "memory");
    #pragma unroll
    for (int kk = 0; kk < 2; ++kk) {
      short8 ap[4], bw[2];
      #pragma unroll
      for (int mf = 0; mf < 4; ++mf) {
        int row = mf * 16 + l15;
        int ch = kk * 4 + l4;
        ap[mf] = *(const short8*)(P + row * 128 + ((ch ^ (row & 7)) * 16));
      }
      #pragma unroll
      for (int nl = 0; nl < 2; ++nl)
        bw[nl] = *(const short8*)(W2T + (size_t)(e * L_ + nl * 16 + l15) * H_ +
                                  dt * 256 + wc * 128 + half * 64 + kk * 32 + l4 * 8);
      #pragma unroll
      for (int mf = 0; mf < 4; ++mf)
        #pragma unroll
        for (int nl = 0; nl < 2; ++nl)
          tacc[mf][nl] =
              __builtin_amdgcn_mfma_f32_16x16x32_bf16(ap[mf], bw[nl], tacc[mf][nl], 0, 0, 0);
    }
    asm volatile("s_waitcnt lgkmcnt(0)" ::: "memory");
  }

  // per-wave t (64x32 f32 = 8KB, overlays own P), cross-wc reduce, atomicAdd
  float* Tr = (float*)smem + w * 2048;
  #pragma unroll
  for (int mf = 0; mf < 4; ++mf)
    #pragma unroll
    for (int nl = 0; nl < 2; ++nl)
      #pragma unroll
      for (int rr = 0; rr < 4; ++rr) {
        int row = mf * 16 + l4 * 4 + rr;
        int col = nl * 16 + l15;
        Tr[row * 32 + col] = tacc[mf][nl][rr];
      }
  __syncthreads();
  float* Tb = (float*)smem;
  #pragma unroll
  for (int jj = 0; jj < 16; ++jj) {
    int ei = tid + jj * 512;                 // [0,8192) = 256 rows x 32 cols
    int srow = ei >> 5, lcol = ei & 31;
    int wr2 = srow >> 6, r6 = srow & 63;
    float sum = Tb[(wr2 * 2 + 0) * 2048 + r6 * 32 + lcol] +
                Tb[(wr2 * 2 + 1) * 2048 + r6 * 32 + lcol];
    if (dt == 0) sum += b2[e * L_ + lcol];
    atomicAdd(out + (size_t)(b * S_ + srow) * L_ + lcol, g * sum);
  }
}

// ---------------- fp32 fallback (no workspace needed) ----------------
__global__ void fb_kernel(const float* __restrict__ x, const float* __restrict__ logits,
                          const float* __restrict__ W1, const float* __restrict__ b1,
                          const float* __restrict__ W2, const float* __restrict__ b2,
                          float* __restrict__ out) {
  int bid = blockIdx.x;
  int e = bid >> 9;
  int r = bid & 511;
  int b = r >> 5, st = r & 31, s0 = st * 8;
  float g = gate_of(lang_of(logits, b), e);
  if (g < GEPS) return;

  __shared__ float xs[8][H_];
  __shared__ unsigned short hs[8][H_];
  int tid = threadIdx.x;
  for (int jj = 0; jj < 32; ++jj) {
    int idx = tid + jj * 256;
    int s = idx >> 10, k = idx & 1023;
    xs[s][k] = x[(size_t)(b * S_ + s0 + s) * H_ + k];
  }
  __syncthreads();
  for (int qq = 0; qq < 4; ++qq) {
    int d = tid + qq * 256;
    float a[8];
    #pragma unroll
    for (int s = 0; s < 8; ++s) a[s] = 0.f;
    for (int k = 0; k < H_; ++k) {
      float wv = W1[((size_t)e << 20) + (size_t)k * H_ + d];
      #pragma unroll
      for (int s = 0; s < 8; ++s) a[s] += xs[s][k] * wv;
    }
    float bv = b1[e * H_ + d];
    #pragma unroll
    for (int s = 0; s < 8; ++s) hs[s][d] = f2bf(fmaxf(a[s] + bv, 0.f));
  }
  __syncthreads();
  int s = tid >> 5, lcol = tid & 31;
  float acc = 0.f;
  for (int d = 0; d < H_; ++d)
    acc += bf2f(hs[s][d]) * W2[(size_t)(e * H_ + d) * L_ + lcol];
  acc += b2[e * L_ + lcol];
  atomicAdd(out + (size_t)(b * S_ + s0 + s) * L_ + lcol, g * acc);
}

extern "C" void kernel_launch(void* const* d_in, const int* in_sizes, int n_in,
                              void* d_out, int out_size, void* d_ws, size_t ws_size,
                              hipStream_t stream) {
  (void)in_sizes; (void)n_in;
  const float* x  = (const float*)d_in[0];
  const float* lg = (const float*)d_in[1];
  const float* W1 = (const float*)d_in[2];
  const float* b1 = (const float*)d_in[3];
  const float* W2 = (const float*)d_in[4];
  const float* b2 = (const float*)d_in[5];
  float* out = (float*)d_out;

  hipMemsetAsync(d_out, 0, (size_t)out_size * sizeof(float), stream);

  const size_t OFF_X = 0;                          // 8 MB bf16 x
  const size_t OFF_W1 = OFF_X + 8388608;           // 22 MB bf16 W1T
  const size_t OFF_W2 = OFF_W1 + 23068672;         // 704 KB bf16 W2T
  const size_t OFF_PLAN = OFF_W2 + 720896;         // [cnt, pairs...]
  const size_t WS_NEED = OFF_PLAN + 1024;

  if (ws_size >= WS_NEED) {
    unsigned short* xbf = (unsigned short*)((char*)d_ws + OFF_X);
    unsigned short* W1T = (unsigned short*)((char*)d_ws + OFF_W1);
    unsigned short* W2T = (unsigned short*)((char*)d_ws + OFF_W2);
    int* plan = (int*)((char*)d_ws + OFF_PLAN);
    prep_kernel<<<2048 + 2816 + 176 + 1, 256, 0, stream>>>(x, lg, W1, W2, xbf, W1T, W2T, plan);
    // grid covers worst case 176 pairs x 4 dt; blocks beyond 4*cnt exit on plan[0]
    ffn_kernel<<<704, 512, 0, stream>>>(xbf, W1T, W2T, b1, b2, lg, plan, out);
  } else {
    fb_kernel<<<E_ * B_ * (S_ / 8), 256, 0, stream>>>(x, lg, W1, b1, W2, b2, out);
  }
}